// Round 18
// baseline (449.942 us; speedup 1.0000x reference)
//
#include <hip/hip_runtime.h>
#include <hip/hip_fp16.h>
#include <math.h>

#define D 64
#define EDIM 16
#define NEG 0.2f
#define SCHUNK 1024
#define PAD 4
#define NT_BLOCKS 1024   // node_transform sub-grid inside the fused dispatch
#define CUNROLL 8        // independent atomics in flight per count thread

typedef _Float16 hh2 __attribute__((ext_vector_type(2)));
typedef unsigned u32x4 __attribute__((ext_vector_type(4)));
union H2cvt { unsigned u; hh2 v; __half2 h; };

#define DPP_XOR1 0xB1
#define DPP_XOR2 0x4E
#define DPP_XOR3 0x1B
template<int CTRL>
__device__ __forceinline__ float dppx(float v)
{
    return __int_as_float(__builtin_amdgcn_mov_dpp(__float_as_int(v), CTRL, 0xF, 0xF, true));
}

// FUSED: blocks [0,NT_BLOCKS) = node_transform layer-1 (VALU-bound);
// blocks [NT_BLOCKS, ...)     = count_deg + rank, 8 edges/thread so each
// thread keeps 8 independent atomics in flight (occupancy is LDS-capped at
// 3 blocks/CU by nt's 48KB -> MLP must come from within the thread).
__global__ void nt_and_count(const float* __restrict__ x,
                             const float* __restrict__ Wl, const float* __restrict__ bl,
                             const float* __restrict__ Wr, const float* __restrict__ br,
                             const float* __restrict__ Lw, const float* __restrict__ Lb,
                             __half* __restrict__ xlh, float* __restrict__ xr,
                             float* __restrict__ res, int N,
                             const int* __restrict__ ei, int* __restrict__ degp,
                             int* __restrict__ rank, int E)
{
    __shared__ float wl[D * D], wr[D * D], lw[D * D];

    if (blockIdx.x >= NT_BLOCKS) {
        // ---------------- count_deg part (8-deep atomic pipeline) ----------
        int bb = (blockIdx.x - NT_BLOCKS) * (blockDim.x * CUNROLL) + threadIdx.x;
        #pragma unroll
        for (int j = 0; j < CUNROLL; j++) {
            int e = bb + j * blockDim.x;            // coalesced per step
            if (e < E) rank[e] = atomicAdd(&degp[ei[E + e] << PAD], 1);
        }
        return;
    }

    // ---------------- node_transform part ----------------
    for (int i = threadIdx.x; i < D * D / 4; i += blockDim.x) {
        ((float4*)wl)[i] = ((const float4*)Wl)[i];
        ((float4*)wr)[i] = ((const float4*)Wr)[i];
        ((float4*)lw)[i] = ((const float4*)Lw)[i];
    }
    int lane = threadIdx.x & 63;
    int wave = __builtin_amdgcn_readfirstlane(threadIdx.x >> 6);   // 0..3
    float vbl = bl[lane], vbr = br[lane], vlb = Lb[lane];
    __syncthreads();

    int gwave  = blockIdx.x * 4 + wave;
    int nwaves = NT_BLOCKS * 4;
    for (int n0 = gwave * 8; n0 < N; n0 += nwaves * 8) {
        float al[8], ar[8], ae[8];
        #pragma unroll
        for (int j = 0; j < 8; j++) { al[j] = vbl; ar[j] = vbr; ae[j] = vlb; }

        if (n0 + 8 <= N) {
            const float* xp0 = x + (size_t)n0 * D;
            #pragma unroll 4
            for (int k = 0; k < D; k++) {
                float w1 = wl[k * D + lane];
                float w2 = wr[k * D + lane];
                float w3 = lw[k * D + lane];
                #pragma unroll
                for (int j = 0; j < 8; j++) {
                    float xv = xp0[j * D + k];       // wave-uniform -> scalar load
                    al[j] = fmaf(xv, w1, al[j]);
                    ar[j] = fmaf(xv, w2, ar[j]);
                    ae[j] = fmaf(xv, w3, ae[j]);
                }
            }
            #pragma unroll
            for (int j = 0; j < 8; j++) {
                int n = n0 + j;
                xlh[(size_t)n * D + lane] = __float2half(al[j]);
                xr[(size_t)n * D + lane]  = ar[j];
                res[(size_t)n * D + lane] = ae[j];
            }
        } else {
            int nr = N - n0;
            for (int k = 0; k < D; k++) {
                float w1 = wl[k * D + lane];
                float w2 = wr[k * D + lane];
                float w3 = lw[k * D + lane];
                for (int j = 0; j < nr; j++) {
                    float xv = x[(size_t)(n0 + j) * D + k];
                    al[j] = fmaf(xv, w1, al[j]);
                    ar[j] = fmaf(xv, w2, ar[j]);
                    ae[j] = fmaf(xv, w3, ae[j]);
                }
            }
            for (int j = 0; j < nr; j++) {
                int n = n0 + j;
                xlh[(size_t)n * D + lane] = __float2half(al[j]);
                xr[(size_t)n * D + lane]  = ar[j];
                res[(size_t)n * D + lane] = ae[j];
            }
        }
    }
}

// plain node_transform for layer 2 (depends on layer-1 output; runs alone)
__global__ void node_transform(const float* __restrict__ x,
                               const float* __restrict__ Wl, const float* __restrict__ bl,
                               const float* __restrict__ Wr, const float* __restrict__ br,
                               const float* __restrict__ Lw, const float* __restrict__ Lb,
                               __half* __restrict__ xlh, float* __restrict__ xr,
                               float* __restrict__ res, int N)
{
    __shared__ float wl[D * D], wr[D * D], lw[D * D];
    for (int i = threadIdx.x; i < D * D / 4; i += blockDim.x) {
        ((float4*)wl)[i] = ((const float4*)Wl)[i];
        ((float4*)wr)[i] = ((const float4*)Wr)[i];
        ((float4*)lw)[i] = ((const float4*)Lw)[i];
    }
    int lane = threadIdx.x & 63;
    int wave = __builtin_amdgcn_readfirstlane(threadIdx.x >> 6);
    float vbl = bl[lane], vbr = br[lane], vlb = Lb[lane];
    __syncthreads();

    int gwave  = blockIdx.x * 4 + wave;
    int nwaves = gridDim.x * 4;
    for (int n0 = gwave * 8; n0 < N; n0 += nwaves * 8) {
        float al[8], ar[8], ae[8];
        #pragma unroll
        for (int j = 0; j < 8; j++) { al[j] = vbl; ar[j] = vbr; ae[j] = vlb; }

        if (n0 + 8 <= N) {
            const float* xp0 = x + (size_t)n0 * D;
            #pragma unroll 4
            for (int k = 0; k < D; k++) {
                float w1 = wl[k * D + lane];
                float w2 = wr[k * D + lane];
                float w3 = lw[k * D + lane];
                #pragma unroll
                for (int j = 0; j < 8; j++) {
                    float xv = xp0[j * D + k];
                    al[j] = fmaf(xv, w1, al[j]);
                    ar[j] = fmaf(xv, w2, ar[j]);
                    ae[j] = fmaf(xv, w3, ae[j]);
                }
            }
            #pragma unroll
            for (int j = 0; j < 8; j++) {
                int n = n0 + j;
                xlh[(size_t)n * D + lane] = __float2half(al[j]);
                xr[(size_t)n * D + lane]  = ar[j];
                res[(size_t)n * D + lane] = ae[j];
            }
        } else {
            int nr = N - n0;
            for (int k = 0; k < D; k++) {
                float w1 = wl[k * D + lane];
                float w2 = wr[k * D + lane];
                float w3 = lw[k * D + lane];
                for (int j = 0; j < nr; j++) {
                    float xv = x[(size_t)(n0 + j) * D + k];
                    al[j] = fmaf(xv, w1, al[j]);
                    ar[j] = fmaf(xv, w2, ar[j]);
                    ae[j] = fmaf(xv, w3, ae[j]);
                }
            }
            for (int j = 0; j < nr; j++) {
                int n = n0 + j;
                xlh[(size_t)n * D + lane] = __float2half(al[j]);
                xr[(size_t)n * D + lane]  = ar[j];
                res[(size_t)n * D + lane] = ae[j];
            }
        }
    }
}

__global__ void scan_blocks(const int* __restrict__ degp, int* __restrict__ rowptr,
                            int* __restrict__ bsum, int N)
{
    __shared__ int tsum[256];
    int t = threadIdx.x;
    int base = blockIdx.x * SCHUNK + t * 4;
    int v0 = 0, v1 = 0, v2 = 0, v3 = 0;
    if (base + 0 < N) v0 = degp[(base + 0) << PAD];
    if (base + 1 < N) v1 = degp[(base + 1) << PAD];
    if (base + 2 < N) v2 = degp[(base + 2) << PAD];
    if (base + 3 < N) v3 = degp[(base + 3) << PAD];
    int local = v0 + v1 + v2 + v3;
    tsum[t] = local;
    __syncthreads();
    for (int off = 1; off < 256; off <<= 1) {
        int x = (t >= off) ? tsum[t - off] : 0;
        __syncthreads();
        tsum[t] += x;
        __syncthreads();
    }
    int excl = tsum[t] - local;
    if (base + 0 < N) rowptr[base + 0] = excl;
    if (base + 1 < N) rowptr[base + 1] = excl + v0;
    if (base + 2 < N) rowptr[base + 2] = excl + v0 + v1;
    if (base + 3 < N) rowptr[base + 3] = excl + v0 + v1 + v2;
    if (t == 0) bsum[blockIdx.x] = tsum[255];
}

__global__ void scan_bsums(int* __restrict__ bsum, int nb, int* __restrict__ rowptrN)
{
    __shared__ int part[256];
    int t = threadIdx.x;
    int C = (nb + 255) / 256;
    int b = t * C, e = min(b + C, nb);
    int sum = 0;
    for (int i = b; i < e; i++) sum += bsum[i];
    part[t] = sum;
    __syncthreads();
    for (int off = 1; off < 256; off <<= 1) {
        int x = (t >= off) ? part[t - off] : 0;
        __syncthreads();
        part[t] += x;
        __syncthreads();
    }
    int running = part[t] - sum;
    for (int i = b; i < e; i++) {
        int v = bsum[i];
        bsum[i] = running;
        running += v;
    }
    if (t == 255) *rowptrN = part[255];
}

__global__ void add_offsets(int* __restrict__ rowptr, const int* __restrict__ bsum, int N)
{
    int i = blockIdx.x * blockDim.x + threadIdx.x;
    if (i < N) rowptr[i] += bsum[i >> 10];
}

// ATOMIC-FREE split scatter, regular stores (L2 write-combining on)
__global__ void scatter_edges(const int* __restrict__ ei, const float* __restrict__ eattr,
                              const int* __restrict__ rowptr, const int* __restrict__ rank,
                              int* __restrict__ esrc, __half* __restrict__ eah, int E)
{
    int e = blockIdx.x * blockDim.x + threadIdx.x;
    if (e >= E) return;
    int dst = ei[E + e];
    int pos = rowptr[dst] + rank[e];
    esrc[pos] = ei[e];
    const float4* s4 = (const float4*)(eattr + (size_t)e * EDIM);
    float4 f0 = s4[0], f1 = s4[1], f2 = s4[2], f3 = s4[3];
    H2cvt c;
    unsigned w[8];
    c.h = __floats2half2_rn(f0.x, f0.y); w[0] = c.u;
    c.h = __floats2half2_rn(f0.z, f0.w); w[1] = c.u;
    c.h = __floats2half2_rn(f1.x, f1.y); w[2] = c.u;
    c.h = __floats2half2_rn(f1.z, f1.w); w[3] = c.u;
    c.h = __floats2half2_rn(f2.x, f2.y); w[4] = c.u;
    c.h = __floats2half2_rn(f2.z, f2.w); w[5] = c.u;
    c.h = __floats2half2_rn(f3.x, f3.y); w[6] = c.u;
    c.h = __floats2half2_rn(f3.z, f3.w); w[7] = c.u;
    u32x4* d4 = (u32x4*)(eah + (size_t)pos * EDIM);
    d4[0] = (u32x4){w[0], w[1], w[2], w[3]};
    d4[1] = (u32x4){w[4], w[5], w[6], w[7]};
}

__device__ __forceinline__ float bpx(float v, int addr)
{
    return __int_as_float(__builtin_amdgcn_ds_bpermute(addr, __float_as_int(v)));
}

__device__ __forceinline__ float edge_dot(const __half* __restrict__ eah, int ee,
                                          const hh2* w2)
{
    const unsigned* ea = (const unsigned*)(eah + (size_t)ee * EDIM);
    float acc = 0.f;
    #pragma unroll
    for (int k = 0; k < 8; k++) {
        H2cvt c; c.u = ea[k];
#if defined(__has_builtin) && __has_builtin(__builtin_amdgcn_fdot2)
        acc = __builtin_amdgcn_fdot2(c.v, w2[k], acc, false);
#else
        acc += (float)(c.v[0] * w2[k][0]) + (float)(c.v[1] * w2[k][1]);
#endif
    }
    return acc;
}

// ONE 64-THREAD BLOCK PER DST NODE; MAX-FREE softmax; shared-exp transpose
// reduce; quad_perm DPP intra-quad; bpermute cross-quad.
__global__ void __launch_bounds__(64) gat_fused(
                          const int* __restrict__ rowptr, const int* __restrict__ esrc,
                          const __half* __restrict__ eah,
                          const float* __restrict__ We, const float* __restrict__ avec,
                          const __half* __restrict__ xlh, const float* __restrict__ xr,
                          const float* __restrict__ res, const float* __restrict__ cb,
                          float* __restrict__ out, int N, int do_relu)
{
    int wid = __builtin_amdgcn_readfirstlane(blockIdx.x);
    int lane = threadIdx.x & 63;
    if (wid >= N) return;

    hh2 w2[8];
    #pragma unroll
    for (int j = 0; j < 8; j++) {
        H2cvt c;
        c.h = __floats2half2_rn(We[(2 * j) * D + lane], We[(2 * j + 1) * D + lane]);
        w2[j] = c.v;
    }
    float av  = avec[lane];
    float xrv = xr[(size_t)wid * D + lane];
    int beg = __builtin_amdgcn_readfirstlane(rowptr[wid]);
    int end = __builtin_amdgcn_readfirstlane(rowptr[wid + 1]);

    const int la4 = lane << 2;
    const int A4 = la4 ^ 16, A8 = la4 ^ 32, A16 = la4 ^ 64, A32 = la4 ^ 128;
    int c0 = lane & 1, c1 = lane & 2;

    float S4 = 0.f, Sr = 0.f, O = 0.f;
    int e = beg;
    for (; e + 8 <= end; e += 8) {
        float pA[4], xA[4], pB[4], xB[4];
        #pragma unroll
        for (int j = 0; j < 4; j++) {
            int s = __builtin_amdgcn_readfirstlane(esrc[e + j]);
            xA[j] = __half2float(xlh[(size_t)s * D + lane]);
            float ew = edge_dot(eah, e + j, w2);
            float m = xA[j] + xrv + ew;
            pA[j] = fmaf(NEG, fminf(m, 0.f), fmaxf(m, 0.f)) * av;
        }
        #pragma unroll
        for (int j = 0; j < 4; j++) {
            int s = __builtin_amdgcn_readfirstlane(esrc[e + 4 + j]);
            xB[j] = __half2float(xlh[(size_t)s * D + lane]);
            float ew = edge_dot(eah, e + 4 + j, w2);
            float m = xB[j] + xrv + ew;
            pB[j] = fmaf(NEG, fminf(m, 0.f), fmaxf(m, 0.f)) * av;
        }
        #pragma unroll
        for (int j = 0; j < 4; j++) { pA[j] += dppx<DPP_XOR1>(pA[j]); pB[j] += dppx<DPP_XOR1>(pB[j]); }
        #pragma unroll
        for (int j = 0; j < 4; j++) { pA[j] += dppx<DPP_XOR2>(pA[j]); pB[j] += dppx<DPP_XOR2>(pB[j]); }
        float vA = c1 ? (c0 ? pA[3] : pA[2]) : (c0 ? pA[1] : pA[0]);
        float vB = c1 ? (c0 ? pB[3] : pB[2]) : (c0 ? pB[1] : pB[0]);
        vA += bpx(vA, A4);  vB += bpx(vB, A4);
        vA += bpx(vA, A8);  vB += bpx(vB, A8);
        vA += bpx(vA, A16); vB += bpx(vB, A16);
        vA += bpx(vA, A32); vB += bpx(vB, A32);
        float evA = __expf(vA), evB = __expf(vB);
        S4 += evA; S4 += evB;
        float qA1 = dppx<DPP_XOR1>(evA), qB1 = dppx<DPP_XOR1>(evB);
        float qA2 = dppx<DPP_XOR2>(evA), qB2 = dppx<DPP_XOR2>(evB);
        float qA3 = dppx<DPP_XOR3>(evA), qB3 = dppx<DPP_XOR3>(evB);
        float y0a = c0 ? xA[1] : xA[0], y0b = c0 ? xA[3] : xA[2];
        float y1a = c0 ? xA[0] : xA[1], y1b = c0 ? xA[2] : xA[3];
        float xcA  = c1 ? y0b : y0a, xc1A = c1 ? y1b : y1a;
        float xc2A = c1 ? y0a : y0b, xc3A = c1 ? y1a : y1b;
        O = fmaf(evA, xcA, fmaf(qA1, xc1A, fmaf(qA2, xc2A, fmaf(qA3, xc3A, O))));
        float z0a = c0 ? xB[1] : xB[0], z0b = c0 ? xB[3] : xB[2];
        float z1a = c0 ? xB[0] : xB[1], z1b = c0 ? xB[2] : xB[3];
        float xcB  = c1 ? z0b : z0a, xc1B = c1 ? z1b : z1a;
        float xc2B = c1 ? z0a : z0b, xc3B = c1 ? z1a : z1b;
        O = fmaf(evB, xcB, fmaf(qB1, xc1B, fmaf(qB2, xc2B, fmaf(qB3, xc3B, O))));
    }
    for (; e + 4 <= end; e += 4) {
        float pp[4], xlv[4];
        #pragma unroll
        for (int j = 0; j < 4; j++) {
            int s = __builtin_amdgcn_readfirstlane(esrc[e + j]);
            xlv[j] = __half2float(xlh[(size_t)s * D + lane]);
            float ew = edge_dot(eah, e + j, w2);
            float m = xlv[j] + xrv + ew;
            pp[j] = fmaf(NEG, fminf(m, 0.f), fmaxf(m, 0.f)) * av;
        }
        #pragma unroll
        for (int j = 0; j < 4; j++) pp[j] += dppx<DPP_XOR1>(pp[j]);
        #pragma unroll
        for (int j = 0; j < 4; j++) pp[j] += dppx<DPP_XOR2>(pp[j]);
        float t0 = c0 ? pp[1] : pp[0];
        float t1 = c0 ? pp[3] : pp[2];
        float v  = c1 ? t1 : t0;
        v += bpx(v, A4); v += bpx(v, A8); v += bpx(v, A16); v += bpx(v, A32);
        float ev = __expf(v);
        S4 += ev;
        float q1 = dppx<DPP_XOR1>(ev);
        float q2 = dppx<DPP_XOR2>(ev);
        float q3 = dppx<DPP_XOR3>(ev);
        float y0a = c0 ? xlv[1] : xlv[0], y0b = c0 ? xlv[3] : xlv[2];
        float y1a = c0 ? xlv[0] : xlv[1], y1b = c0 ? xlv[2] : xlv[3];
        float x_c  = c1 ? y0b : y0a;
        float x_c1 = c1 ? y1b : y1a;
        float x_c2 = c1 ? y0a : y0b;
        float x_c3 = c1 ? y1a : y1b;
        O = fmaf(ev, x_c, fmaf(q1, x_c1, fmaf(q2, x_c2, fmaf(q3, x_c3, O))));
    }
    for (; e < end; ++e) {
        int s = __builtin_amdgcn_readfirstlane(esrc[e]);
        float xlv = __half2float(xlh[(size_t)s * D + lane]);
        float ew = edge_dot(eah, e, w2);
        float m = xlv + xrv + ew;
        float p = fmaf(NEG, fminf(m, 0.f), fmaxf(m, 0.f)) * av;
        p += dppx<DPP_XOR1>(p); p += dppx<DPP_XOR2>(p);
        p += bpx(p, A4); p += bpx(p, A8); p += bpx(p, A16); p += bpx(p, A32);
        float w = __expf(p);
        Sr += w;
        O = fmaf(w, xlv, O);
    }
    S4 += dppx<DPP_XOR1>(S4);
    S4 += dppx<DPP_XOR2>(S4);
    float S = S4 + Sr;

    float v = O / (S + 1e-16f) + cb[lane] + res[(size_t)wid * D + lane];
    if (do_relu) v = fmaxf(v, 0.f);
    out[(size_t)wid * D + lane] = v;
}

extern "C" void kernel_launch(void* const* d_in, const int* in_sizes, int n_in,
                              void* d_out, int out_size, void* d_ws, size_t ws_size,
                              hipStream_t stream)
{
    const float* x     = (const float*)d_in[0];
    const int*   ei    = (const int*)d_in[1];
    const float* eattr = (const float*)d_in[2];
    const float* Wl1 = (const float*)d_in[3];  const float* bl1 = (const float*)d_in[4];
    const float* Wr1 = (const float*)d_in[5];  const float* br1 = (const float*)d_in[6];
    const float* We1 = (const float*)d_in[7];  const float* a1  = (const float*)d_in[8];
    const float* cb1 = (const float*)d_in[9];
    const float* L1w = (const float*)d_in[10]; const float* L1b = (const float*)d_in[11];
    const float* Wl2 = (const float*)d_in[12]; const float* bl2 = (const float*)d_in[13];
    const float* Wr2 = (const float*)d_in[14]; const float* br2 = (const float*)d_in[15];
    const float* We2 = (const float*)d_in[16]; const float* a2  = (const float*)d_in[17];
    const float* cb2 = (const float*)d_in[18];
    const float* L2w = (const float*)d_in[19]; const float* L2b = (const float*)d_in[20];

    const int N = in_sizes[0] / D;
    const int E = in_sizes[1] / 2;
    const int NB = (N + SCHUNK - 1) / SCHUNK;

    char* wsb = (char*)d_ws;
    float*  xr   = (float*)wsb;  wsb += (size_t)N * D * sizeof(float);
    float*  res  = (float*)wsb;  wsb += (size_t)N * D * sizeof(float);
    __half* xlh  = (__half*)wsb; wsb += (size_t)N * D * sizeof(__half);
    __half* eah  = (__half*)wsb; wsb += (size_t)E * EDIM * sizeof(__half);
    int* esrc    = (int*)wsb;    wsb += (size_t)E * sizeof(int);
    int* rowptr  = (int*)wsb;    wsb += (size_t)(N + 1) * sizeof(int);
    int* bsum    = (int*)wsb;    wsb += (size_t)NB * sizeof(int);
    // DEDICATED (count_deg runs concurrently with node_transform L1):
    int* degp    = (int*)wsb;    wsb += ((size_t)N << PAD) * sizeof(int);   // 6.4MB
    int* rank    = (int*)wsb;    wsb += (size_t)E * sizeof(int);            // 6.4MB

    float* out = (float*)d_out;   // doubles as h between layers

    const int et = (E + 255) / 256;
    const int cb_blocks = (E + 256 * CUNROLL - 1) / (256 * CUNROLL);

    // -------- fused: node_transform L1 (VALU) || count_deg+rank (atomics) ------
    hipMemsetAsync(degp, 0, ((size_t)N << PAD) * sizeof(int), stream);
    nt_and_count<<<NT_BLOCKS + cb_blocks, 256, 0, stream>>>(
        x, Wl1, bl1, Wr1, br1, L1w, L1b, xlh, xr, res, N,
        ei, degp, rank, E);

    // -------- rest of CSR build --------
    scan_blocks<<<NB, 256, 0, stream>>>(degp, rowptr, bsum, N);
    scan_bsums<<<1, 256, 0, stream>>>(bsum, NB, rowptr + N);
    add_offsets<<<(N + 255) / 256, 256, 0, stream>>>(rowptr, bsum, N);
    scatter_edges<<<et, 256, 0, stream>>>(ei, eattr, rowptr, rank, esrc, eah, E);

    // ---------------- layer 1 ----------------
    gat_fused<<<N, 64, 0, stream>>>(rowptr, esrc, eah, We1, a1,
                                    xlh, xr, res, cb1, out, N, 1);

    // ---------------- layer 2 (reads layer-1 result from d_out) ----------------
    node_transform<<<1024, 256, 0, stream>>>(out, Wl2, bl2, Wr2, br2, L2w, L2b,
                                             xlh, xr, res, N);
    gat_fused<<<N, 64, 0, stream>>>(rowptr, esrc, eah, We2, a2,
                                    xlh, xr, res, cb2, out, N, 0);
}

// Round 19
// 427.886 us; speedup vs baseline: 1.0515x; 1.0515x over previous
//
#include <hip/hip_runtime.h>
#include <hip/hip_fp16.h>
#include <math.h>

#define D 64
#define EDIM 16
#define NEG 0.2f
#define SCHUNK 1024
#define PAD 4
#define NT_BLOCKS 1024   // node_transform sub-grid inside the fused dispatch
#define CUNROLL 8        // independent atomics in flight per count thread

typedef _Float16 hh2 __attribute__((ext_vector_type(2)));
typedef unsigned u32x4 __attribute__((ext_vector_type(4)));
union H2cvt { unsigned u; hh2 v; __half2 h; };

#define DPP_XOR1 0xB1
#define DPP_XOR2 0x4E
#define DPP_XOR3 0x1B
template<int CTRL>
__device__ __forceinline__ float dppx(float v)
{
    return __int_as_float(__builtin_amdgcn_mov_dpp(__float_as_int(v), CTRL, 0xF, 0xF, true));
}

// node_transform body, NO LDS: W columns read directly from global each k
// (coalesced 256B wave-loads, L1/L2-resident working set of 48KB). x rows via
// wave-uniform scalar loads. LDS-free -> occupancy is VGPR-bound (~8 blk/CU).
__device__ __forceinline__ void nt_body(const float* __restrict__ x,
                                        const float* __restrict__ Wl, const float* __restrict__ bl,
                                        const float* __restrict__ Wr, const float* __restrict__ br,
                                        const float* __restrict__ Lw, const float* __restrict__ Lb,
                                        __half* __restrict__ xlh, float* __restrict__ xr,
                                        float* __restrict__ res, int N,
                                        int gwave, int nwaves, int lane)
{
    float vbl = bl[lane], vbr = br[lane], vlb = Lb[lane];
    for (int n0 = gwave * 8; n0 < N; n0 += nwaves * 8) {
        float al[8], ar[8], ae[8];
        #pragma unroll
        for (int j = 0; j < 8; j++) { al[j] = vbl; ar[j] = vbr; ae[j] = vlb; }

        if (n0 + 8 <= N) {
            const float* xp0 = x + (size_t)n0 * D;
            #pragma unroll 4
            for (int k = 0; k < D; k++) {
                float w1 = Wl[k * D + lane];
                float w2 = Wr[k * D + lane];
                float w3 = Lw[k * D + lane];
                #pragma unroll
                for (int j = 0; j < 8; j++) {
                    float xv = xp0[j * D + k];       // wave-uniform -> scalar load
                    al[j] = fmaf(xv, w1, al[j]);
                    ar[j] = fmaf(xv, w2, ar[j]);
                    ae[j] = fmaf(xv, w3, ae[j]);
                }
            }
            #pragma unroll
            for (int j = 0; j < 8; j++) {
                int n = n0 + j;
                xlh[(size_t)n * D + lane] = __float2half(al[j]);
                xr[(size_t)n * D + lane]  = ar[j];
                res[(size_t)n * D + lane] = ae[j];
            }
        } else {
            int nr = N - n0;
            for (int k = 0; k < D; k++) {
                float w1 = Wl[k * D + lane];
                float w2 = Wr[k * D + lane];
                float w3 = Lw[k * D + lane];
                for (int j = 0; j < nr; j++) {
                    float xv = x[(size_t)(n0 + j) * D + k];
                    al[j] = fmaf(xv, w1, al[j]);
                    ar[j] = fmaf(xv, w2, ar[j]);
                    ae[j] = fmaf(xv, w3, ae[j]);
                }
            }
            for (int j = 0; j < nr; j++) {
                int n = n0 + j;
                xlh[(size_t)n * D + lane] = __float2half(al[j]);
                xr[(size_t)n * D + lane]  = ar[j];
                res[(size_t)n * D + lane] = ae[j];
            }
        }
    }
}

// FUSED: blocks [0,NT_BLOCKS) = node_transform layer-1 (VALU-bound, LDS-free);
// blocks [NT_BLOCKS, ...) = count_deg+rank, CUNROLL atomics in flight/thread.
__global__ void nt_and_count(const float* __restrict__ x,
                             const float* __restrict__ Wl, const float* __restrict__ bl,
                             const float* __restrict__ Wr, const float* __restrict__ br,
                             const float* __restrict__ Lw, const float* __restrict__ Lb,
                             __half* __restrict__ xlh, float* __restrict__ xr,
                             float* __restrict__ res, int N,
                             const int* __restrict__ ei, int* __restrict__ degp,
                             int* __restrict__ rank, int E)
{
    if (blockIdx.x >= NT_BLOCKS) {
        int bb = (blockIdx.x - NT_BLOCKS) * (blockDim.x * CUNROLL) + threadIdx.x;
        #pragma unroll
        for (int j = 0; j < CUNROLL; j++) {
            int e = bb + j * blockDim.x;            // coalesced per step
            if (e < E) rank[e] = atomicAdd(&degp[ei[E + e] << PAD], 1);
        }
        return;
    }
    int lane = threadIdx.x & 63;
    int wave = __builtin_amdgcn_readfirstlane(threadIdx.x >> 6);   // 0..3
    nt_body(x, Wl, bl, Wr, br, Lw, Lb, xlh, xr, res, N,
            blockIdx.x * 4 + wave, NT_BLOCKS * 4, lane);
}

// plain node_transform for layer 2 (LDS-free)
__global__ void node_transform(const float* __restrict__ x,
                               const float* __restrict__ Wl, const float* __restrict__ bl,
                               const float* __restrict__ Wr, const float* __restrict__ br,
                               const float* __restrict__ Lw, const float* __restrict__ Lb,
                               __half* __restrict__ xlh, float* __restrict__ xr,
                               float* __restrict__ res, int N)
{
    int lane = threadIdx.x & 63;
    int wave = __builtin_amdgcn_readfirstlane(threadIdx.x >> 6);
    nt_body(x, Wl, bl, Wr, br, Lw, Lb, xlh, xr, res, N,
            blockIdx.x * 4 + wave, gridDim.x * 4, lane);
}

__global__ void scan_blocks(const int* __restrict__ degp, int* __restrict__ rowptr,
                            int* __restrict__ bsum, int N)
{
    __shared__ int tsum[256];
    int t = threadIdx.x;
    int base = blockIdx.x * SCHUNK + t * 4;
    int v0 = 0, v1 = 0, v2 = 0, v3 = 0;
    if (base + 0 < N) v0 = degp[(base + 0) << PAD];
    if (base + 1 < N) v1 = degp[(base + 1) << PAD];
    if (base + 2 < N) v2 = degp[(base + 2) << PAD];
    if (base + 3 < N) v3 = degp[(base + 3) << PAD];
    int local = v0 + v1 + v2 + v3;
    tsum[t] = local;
    __syncthreads();
    for (int off = 1; off < 256; off <<= 1) {
        int x = (t >= off) ? tsum[t - off] : 0;
        __syncthreads();
        tsum[t] += x;
        __syncthreads();
    }
    int excl = tsum[t] - local;
    if (base + 0 < N) rowptr[base + 0] = excl;
    if (base + 1 < N) rowptr[base + 1] = excl + v0;
    if (base + 2 < N) rowptr[base + 2] = excl + v0 + v1;
    if (base + 3 < N) rowptr[base + 3] = excl + v0 + v1 + v2;
    if (t == 0) bsum[blockIdx.x] = tsum[255];
}

__global__ void scan_bsums(int* __restrict__ bsum, int nb, int* __restrict__ rowptrN)
{
    __shared__ int part[256];
    int t = threadIdx.x;
    int C = (nb + 255) / 256;
    int b = t * C, e = min(b + C, nb);
    int sum = 0;
    for (int i = b; i < e; i++) sum += bsum[i];
    part[t] = sum;
    __syncthreads();
    for (int off = 1; off < 256; off <<= 1) {
        int x = (t >= off) ? part[t - off] : 0;
        __syncthreads();
        part[t] += x;
        __syncthreads();
    }
    int running = part[t] - sum;
    for (int i = b; i < e; i++) {
        int v = bsum[i];
        bsum[i] = running;
        running += v;
    }
    if (t == 255) *rowptrN = part[255];
}

__global__ void add_offsets(int* __restrict__ rowptr, const int* __restrict__ bsum, int N)
{
    int i = blockIdx.x * blockDim.x + threadIdx.x;
    if (i < N) rowptr[i] += bsum[i >> 10];
}

// ATOMIC-FREE split scatter, regular stores (L2 write-combining on)
__global__ void scatter_edges(const int* __restrict__ ei, const float* __restrict__ eattr,
                              const int* __restrict__ rowptr, const int* __restrict__ rank,
                              int* __restrict__ esrc, __half* __restrict__ eah, int E)
{
    int e = blockIdx.x * blockDim.x + threadIdx.x;
    if (e >= E) return;
    int dst = ei[E + e];
    int pos = rowptr[dst] + rank[e];
    esrc[pos] = ei[e];
    const float4* s4 = (const float4*)(eattr + (size_t)e * EDIM);
    float4 f0 = s4[0], f1 = s4[1], f2 = s4[2], f3 = s4[3];
    H2cvt c;
    unsigned w[8];
    c.h = __floats2half2_rn(f0.x, f0.y); w[0] = c.u;
    c.h = __floats2half2_rn(f0.z, f0.w); w[1] = c.u;
    c.h = __floats2half2_rn(f1.x, f1.y); w[2] = c.u;
    c.h = __floats2half2_rn(f1.z, f1.w); w[3] = c.u;
    c.h = __floats2half2_rn(f2.x, f2.y); w[4] = c.u;
    c.h = __floats2half2_rn(f2.z, f2.w); w[5] = c.u;
    c.h = __floats2half2_rn(f3.x, f3.y); w[6] = c.u;
    c.h = __floats2half2_rn(f3.z, f3.w); w[7] = c.u;
    u32x4* d4 = (u32x4*)(eah + (size_t)pos * EDIM);
    d4[0] = (u32x4){w[0], w[1], w[2], w[3]};
    d4[1] = (u32x4){w[4], w[5], w[6], w[7]};
}

__device__ __forceinline__ float bpx(float v, int addr)
{
    return __int_as_float(__builtin_amdgcn_ds_bpermute(addr, __float_as_int(v)));
}

__device__ __forceinline__ float edge_dot(const __half* __restrict__ eah, int ee,
                                          const hh2* w2)
{
    const unsigned* ea = (const unsigned*)(eah + (size_t)ee * EDIM);
    float acc = 0.f;
    #pragma unroll
    for (int k = 0; k < 8; k++) {
        H2cvt c; c.u = ea[k];
#if defined(__has_builtin) && __has_builtin(__builtin_amdgcn_fdot2)
        acc = __builtin_amdgcn_fdot2(c.v, w2[k], acc, false);
#else
        acc += (float)(c.v[0] * w2[k][0]) + (float)(c.v[1] * w2[k][1]);
#endif
    }
    return acc;
}

// ONE 64-THREAD BLOCK PER DST NODE; MAX-FREE softmax; shared-exp transpose
// reduce; quad_perm DPP intra-quad; bpermute cross-quad.
__global__ void __launch_bounds__(64) gat_fused(
                          const int* __restrict__ rowptr, const int* __restrict__ esrc,
                          const __half* __restrict__ eah,
                          const float* __restrict__ We, const float* __restrict__ avec,
                          const __half* __restrict__ xlh, const float* __restrict__ xr,
                          const float* __restrict__ res, const float* __restrict__ cb,
                          float* __restrict__ out, int N, int do_relu)
{
    int wid = __builtin_amdgcn_readfirstlane(blockIdx.x);
    int lane = threadIdx.x & 63;
    if (wid >= N) return;

    hh2 w2[8];
    #pragma unroll
    for (int j = 0; j < 8; j++) {
        H2cvt c;
        c.h = __floats2half2_rn(We[(2 * j) * D + lane], We[(2 * j + 1) * D + lane]);
        w2[j] = c.v;
    }
    float av  = avec[lane];
    float xrv = xr[(size_t)wid * D + lane];
    int beg = __builtin_amdgcn_readfirstlane(rowptr[wid]);
    int end = __builtin_amdgcn_readfirstlane(rowptr[wid + 1]);

    const int la4 = lane << 2;
    const int A4 = la4 ^ 16, A8 = la4 ^ 32, A16 = la4 ^ 64, A32 = la4 ^ 128;
    int c0 = lane & 1, c1 = lane & 2;

    float S4 = 0.f, Sr = 0.f, O = 0.f;
    int e = beg;
    for (; e + 8 <= end; e += 8) {
        float pA[4], xA[4], pB[4], xB[4];
        #pragma unroll
        for (int j = 0; j < 4; j++) {
            int s = __builtin_amdgcn_readfirstlane(esrc[e + j]);
            xA[j] = __half2float(xlh[(size_t)s * D + lane]);
            float ew = edge_dot(eah, e + j, w2);
            float m = xA[j] + xrv + ew;
            pA[j] = fmaf(NEG, fminf(m, 0.f), fmaxf(m, 0.f)) * av;
        }
        #pragma unroll
        for (int j = 0; j < 4; j++) {
            int s = __builtin_amdgcn_readfirstlane(esrc[e + 4 + j]);
            xB[j] = __half2float(xlh[(size_t)s * D + lane]);
            float ew = edge_dot(eah, e + 4 + j, w2);
            float m = xB[j] + xrv + ew;
            pB[j] = fmaf(NEG, fminf(m, 0.f), fmaxf(m, 0.f)) * av;
        }
        #pragma unroll
        for (int j = 0; j < 4; j++) { pA[j] += dppx<DPP_XOR1>(pA[j]); pB[j] += dppx<DPP_XOR1>(pB[j]); }
        #pragma unroll
        for (int j = 0; j < 4; j++) { pA[j] += dppx<DPP_XOR2>(pA[j]); pB[j] += dppx<DPP_XOR2>(pB[j]); }
        float vA = c1 ? (c0 ? pA[3] : pA[2]) : (c0 ? pA[1] : pA[0]);
        float vB = c1 ? (c0 ? pB[3] : pB[2]) : (c0 ? pB[1] : pB[0]);
        vA += bpx(vA, A4);  vB += bpx(vB, A4);
        vA += bpx(vA, A8);  vB += bpx(vB, A8);
        vA += bpx(vA, A16); vB += bpx(vB, A16);
        vA += bpx(vA, A32); vB += bpx(vB, A32);
        float evA = __expf(vA), evB = __expf(vB);
        S4 += evA; S4 += evB;
        float qA1 = dppx<DPP_XOR1>(evA), qB1 = dppx<DPP_XOR1>(evB);
        float qA2 = dppx<DPP_XOR2>(evA), qB2 = dppx<DPP_XOR2>(evB);
        float qA3 = dppx<DPP_XOR3>(evA), qB3 = dppx<DPP_XOR3>(evB);
        float y0a = c0 ? xA[1] : xA[0], y0b = c0 ? xA[3] : xA[2];
        float y1a = c0 ? xA[0] : xA[1], y1b = c0 ? xA[2] : xA[3];
        float xcA  = c1 ? y0b : y0a, xc1A = c1 ? y1b : y1a;
        float xc2A = c1 ? y0a : y0b, xc3A = c1 ? y1a : y1b;
        O = fmaf(evA, xcA, fmaf(qA1, xc1A, fmaf(qA2, xc2A, fmaf(qA3, xc3A, O))));
        float z0a = c0 ? xB[1] : xB[0], z0b = c0 ? xB[3] : xB[2];
        float z1a = c0 ? xB[0] : xB[1], z1b = c0 ? xB[2] : xB[3];
        float xcB  = c1 ? z0b : z0a, xc1B = c1 ? z1b : z1a;
        float xc2B = c1 ? z0a : z0b, xc3B = c1 ? z1a : z1b;
        O = fmaf(evB, xcB, fmaf(qB1, xc1B, fmaf(qB2, xc2B, fmaf(qB3, xc3B, O))));
    }
    for (; e + 4 <= end; e += 4) {
        float pp[4], xlv[4];
        #pragma unroll
        for (int j = 0; j < 4; j++) {
            int s = __builtin_amdgcn_readfirstlane(esrc[e + j]);
            xlv[j] = __half2float(xlh[(size_t)s * D + lane]);
            float ew = edge_dot(eah, e + j, w2);
            float m = xlv[j] + xrv + ew;
            pp[j] = fmaf(NEG, fminf(m, 0.f), fmaxf(m, 0.f)) * av;
        }
        #pragma unroll
        for (int j = 0; j < 4; j++) pp[j] += dppx<DPP_XOR1>(pp[j]);
        #pragma unroll
        for (int j = 0; j < 4; j++) pp[j] += dppx<DPP_XOR2>(pp[j]);
        float t0 = c0 ? pp[1] : pp[0];
        float t1 = c0 ? pp[3] : pp[2];
        float v  = c1 ? t1 : t0;
        v += bpx(v, A4); v += bpx(v, A8); v += bpx(v, A16); v += bpx(v, A32);
        float ev = __expf(v);
        S4 += ev;
        float q1 = dppx<DPP_XOR1>(ev);
        float q2 = dppx<DPP_XOR2>(ev);
        float q3 = dppx<DPP_XOR3>(ev);
        float y0a = c0 ? xlv[1] : xlv[0], y0b = c0 ? xlv[3] : xlv[2];
        float y1a = c0 ? xlv[0] : xlv[1], y1b = c0 ? xlv[2] : xlv[3];
        float x_c  = c1 ? y0b : y0a;
        float x_c1 = c1 ? y1b : y1a;
        float x_c2 = c1 ? y0a : y0b;
        float x_c3 = c1 ? y1a : y1b;
        O = fmaf(ev, x_c, fmaf(q1, x_c1, fmaf(q2, x_c2, fmaf(q3, x_c3, O))));
    }
    for (; e < end; ++e) {
        int s = __builtin_amdgcn_readfirstlane(esrc[e]);
        float xlv = __half2float(xlh[(size_t)s * D + lane]);
        float ew = edge_dot(eah, e, w2);
        float m = xlv + xrv + ew;
        float p = fmaf(NEG, fminf(m, 0.f), fmaxf(m, 0.f)) * av;
        p += dppx<DPP_XOR1>(p); p += dppx<DPP_XOR2>(p);
        p += bpx(p, A4); p += bpx(p, A8); p += bpx(p, A16); p += bpx(p, A32);
        float w = __expf(p);
        Sr += w;
        O = fmaf(w, xlv, O);
    }
    S4 += dppx<DPP_XOR1>(S4);
    S4 += dppx<DPP_XOR2>(S4);
    float S = S4 + Sr;

    float v = O / (S + 1e-16f) + cb[lane] + res[(size_t)wid * D + lane];
    if (do_relu) v = fmaxf(v, 0.f);
    out[(size_t)wid * D + lane] = v;
}

extern "C" void kernel_launch(void* const* d_in, const int* in_sizes, int n_in,
                              void* d_out, int out_size, void* d_ws, size_t ws_size,
                              hipStream_t stream)
{
    const float* x     = (const float*)d_in[0];
    const int*   ei    = (const int*)d_in[1];
    const float* eattr = (const float*)d_in[2];
    const float* Wl1 = (const float*)d_in[3];  const float* bl1 = (const float*)d_in[4];
    const float* Wr1 = (const float*)d_in[5];  const float* br1 = (const float*)d_in[6];
    const float* We1 = (const float*)d_in[7];  const float* a1  = (const float*)d_in[8];
    const float* cb1 = (const float*)d_in[9];
    const float* L1w = (const float*)d_in[10]; const float* L1b = (const float*)d_in[11];
    const float* Wl2 = (const float*)d_in[12]; const float* bl2 = (const float*)d_in[13];
    const float* Wr2 = (const float*)d_in[14]; const float* br2 = (const float*)d_in[15];
    const float* We2 = (const float*)d_in[16]; const float* a2  = (const float*)d_in[17];
    const float* cb2 = (const float*)d_in[18];
    const float* L2w = (const float*)d_in[19]; const float* L2b = (const float*)d_in[20];

    const int N = in_sizes[0] / D;
    const int E = in_sizes[1] / 2;
    const int NB = (N + SCHUNK - 1) / SCHUNK;

    char* wsb = (char*)d_ws;
    float*  xr   = (float*)wsb;  wsb += (size_t)N * D * sizeof(float);
    float*  res  = (float*)wsb;  wsb += (size_t)N * D * sizeof(float);
    __half* xlh  = (__half*)wsb; wsb += (size_t)N * D * sizeof(__half);
    __half* eah  = (__half*)wsb; wsb += (size_t)E * EDIM * sizeof(__half);
    int* esrc    = (int*)wsb;    wsb += (size_t)E * sizeof(int);
    int* rowptr  = (int*)wsb;    wsb += (size_t)(N + 1) * sizeof(int);
    int* bsum    = (int*)wsb;    wsb += (size_t)NB * sizeof(int);
    // DEDICATED (count runs concurrently with node_transform L1):
    int* degp    = (int*)wsb;    wsb += ((size_t)N << PAD) * sizeof(int);   // 6.4MB
    int* rank    = (int*)wsb;    wsb += (size_t)E * sizeof(int);            // 6.4MB

    float* out = (float*)d_out;   // doubles as h between layers

    const int et = (E + 255) / 256;
    const int cb_blocks = (E + 256 * CUNROLL - 1) / (256 * CUNROLL);

    // -------- fused: node_transform L1 (VALU) || count_deg+rank (atomics) ------
    hipMemsetAsync(degp, 0, ((size_t)N << PAD) * sizeof(int), stream);
    nt_and_count<<<NT_BLOCKS + cb_blocks, 256, 0, stream>>>(
        x, Wl1, bl1, Wr1, br1, L1w, L1b, xlh, xr, res, N,
        ei, degp, rank, E);

    // -------- rest of CSR build --------
    scan_blocks<<<NB, 256, 0, stream>>>(degp, rowptr, bsum, N);
    scan_bsums<<<1, 256, 0, stream>>>(bsum, NB, rowptr + N);
    add_offsets<<<(N + 255) / 256, 256, 0, stream>>>(rowptr, bsum, N);
    scatter_edges<<<et, 256, 0, stream>>>(ei, eattr, rowptr, rank, esrc, eah, E);

    // ---------------- layer 1 ----------------
    gat_fused<<<N, 64, 0, stream>>>(rowptr, esrc, eah, We1, a1,
                                    xlh, xr, res, cb1, out, N, 1);

    // ---------------- layer 2 (reads layer-1 result from d_out) ----------------
    node_transform<<<1024, 256, 0, stream>>>(out, Wl2, bl2, Wr2, br2, L2w, L2b,
                                             xlh, xr, res, N);
    gat_fused<<<N, 64, 0, stream>>>(rowptr, esrc, eah, We2, a2,
                                    xlh, xr, res, cb2, out, N, 0);
}